// Round 1
// baseline (232.600 us; speedup 1.0000x reference)
//
#include <hip/hip_runtime.h>

#define N 2048
#define ONW 4096

__global__ __launch_bounds__(256) void hdblut_kernel(
    const int* __restrict__ img, const float4* __restrict__ w4,
    float* __restrict__ out)
{
    __shared__ int tile[20][21];
    const int tx = threadIdx.x, ty = threadIdx.y;
    const int bx = blockIdx.x * 16, by = blockIdx.y * 16;
    const int tid = ty * 16 + tx;

    // cooperative load of 20x20 halo tile with border reflection
    #pragma unroll
    for (int t = 0; t < 2; ++t) {
        int e = tid + t * 256;
        if (e < 400) {
            int rr = e / 20, cc = e % 20;
            int gi = by + rr - 2, gj = bx + cc - 2;
            gi = gi < 0 ? -gi : (gi >= N ? 2 * N - 2 - gi : gi);
            gj = gj < 0 ? -gj : (gj >= N ? 2 * N - 2 - gj : gj);
            tile[rr][cc] = img[gi * N + gj];
        }
    }
    __syncthreads();

    // 5x5 neighborhood into registers
    int n[5][5];
    #pragma unroll
    for (int di = 0; di < 5; ++di)
        #pragma unroll
        for (int dj = 0; dj < 5; ++dj)
            n[di][dj] = tile[ty + di][tx + dj];

    const int a = n[2][2];
    float o0 = 0.f, o1 = 0.f, o2 = 0.f, o3 = 0.f;

    // rotated-frame b/c offsets per k (from _OFFSETS)
    const int bo[3][2] = {{0, 1}, {1, 1}, {1, 2}};
    const int co[3][2] = {{0, 2}, {2, 2}, {2, 1}};

    #pragma unroll
    for (int r = 0; r < 4; ++r) {
        #pragma unroll
        for (int k = 0; k < 3; ++k) {
            const int bp = bo[k][0], bq = bo[k][1];
            const int cp = co[k][0], cq = co[k][1];
            // rotate offset (p,q) by r into original-frame (di,dj)
            const int bdi = (r == 0) ? bp : (r == 1) ? bq : (r == 2) ? -bp : -bq;
            const int bdj = (r == 0) ? bq : (r == 1) ? -bp : (r == 2) ? -bq : bp;
            const int cdi = (r == 0) ? cp : (r == 1) ? cq : (r == 2) ? -cp : -cq;
            const int cdj = (r == 0) ? cq : (r == 1) ? -cp : (r == 2) ? -cq : cp;
            const int b = n[2 + bdi][2 + bdj];
            const int c = n[2 + cdi][2 + cdj];
            const float4 wv = w4[(k << 12) | (a << 8) | (b << 4) | c];
            // inverse-rotation permutation of the 2x2 sub-pixels
            if (r == 0)      { o0 += wv.x; o1 += wv.y; o2 += wv.z; o3 += wv.w; }
            else if (r == 1) { o0 += wv.z; o1 += wv.x; o2 += wv.w; o3 += wv.y; }
            else if (r == 2) { o0 += wv.w; o1 += wv.z; o2 += wv.y; o3 += wv.x; }
            else             { o0 += wv.y; o1 += wv.w; o2 += wv.x; o3 += wv.z; }
        }
    }

    const float s = 1.0f / 3.0f;
    const int oy = (by + ty) * 2, ox = (bx + tx) * 2;
    float2* op = (float2*)out;
    op[(oy * ONW + ox) >> 1]       = make_float2(o0 * s, o1 * s);
    op[((oy + 1) * ONW + ox) >> 1] = make_float2(o2 * s, o3 * s);
}

extern "C" void kernel_launch(void* const* d_in, const int* in_sizes, int n_in,
                              void* d_out, int out_size, void* d_ws, size_t ws_size,
                              hipStream_t stream)
{
    const int* img = (const int*)d_in[0];
    const float4* w4 = (const float4*)d_in[1];
    float* out = (float*)d_out;
    dim3 block(16, 16);
    dim3 grid(N / 16, N / 16);
    hdblut_kernel<<<grid, block, 0, stream>>>(img, w4, out);
}

// Round 2
// 118.948 us; speedup vs baseline: 1.9555x; 1.9555x over previous
//
#include <hip/hip_runtime.h>
#include <hip/hip_fp16.h>

#define N 2048
#define ONW 4096
#define TS 72                         // halo tile row stride (ints), even
#define LUT_BYTES (12288 * 8)         // 3*16^3 entries * 4 fp16 = 98304 B
#define TILE_BYTES (68 * TS * 4)      // 19584 B
#define SMEM_BYTES (LUT_BYTES + TILE_BYTES)

typedef _Float16 half4 __attribute__((ext_vector_type(4)));

__global__ __launch_bounds__(1024) void hdblut_kernel(
    const int* __restrict__ img, const float4* __restrict__ w4,
    float* __restrict__ out)
{
    extern __shared__ unsigned char smem[];
    half4* lut = (half4*)smem;                       // [12288] 8B entries
    int* tile = (int*)(smem + LUT_BYTES);            // [68][TS]

    const int tx = threadIdx.x, ty = threadIdx.y;
    const int tid = ty * 32 + tx;
    const int bx0 = blockIdx.x * 64, by0 = blockIdx.y * 64;

    // 1) convert fp32 LUT -> fp16 LDS (12288 float4 entries)
    #pragma unroll
    for (int i = 0; i < 12; ++i) {
        int j = tid + i * 1024;
        float4 v = w4[j];
        half4 h;
        h.x = (_Float16)v.x; h.y = (_Float16)v.y;
        h.z = (_Float16)v.z; h.w = (_Float16)v.w;
        lut[j] = h;
    }

    // 2) 68x68 halo tile with border reflection
    for (int e = tid; e < 68 * 68; e += 1024) {
        int rr = e / 68, cc = e % 68;
        int gi = by0 + rr - 2, gj = bx0 + cc - 2;
        gi = gi < 0 ? -gi : (gi >= N ? 2 * N - 2 - gi : gi);
        gj = gj < 0 ? -gj : (gj >= N ? 2 * N - 2 - gj : gj);
        tile[rr * TS + cc] = img[gi * N + gj];
    }
    __syncthreads();

    // 3) 6x6 neighborhood for this thread's 2x2 pixel patch (b64 reads)
    int n[6][6];
    {
        const int r0 = ty * 2, c0 = tx * 2;
        #pragma unroll
        for (int r = 0; r < 6; ++r)
            #pragma unroll
            for (int j = 0; j < 3; ++j) {
                int2 t2 = *(const int2*)&tile[(r0 + r) * TS + c0 + 2 * j];
                n[r][2 * j] = t2.x; n[r][2 * j + 1] = t2.y;
            }
    }

    float acc[2][2][4];
    #pragma unroll
    for (int i = 0; i < 2; ++i)
        #pragma unroll
        for (int j = 0; j < 2; ++j)
            #pragma unroll
            for (int c = 0; c < 4; ++c) acc[i][j][c] = 0.f;

    const int bo[3][2] = {{0, 1}, {1, 1}, {1, 2}};
    const int co[3][2] = {{0, 2}, {2, 2}, {2, 1}};

    #pragma unroll
    for (int pi = 0; pi < 2; ++pi) {
      #pragma unroll
      for (int pj = 0; pj < 2; ++pj) {
        const int av = n[2 + pi][2 + pj];
        #pragma unroll
        for (int r = 0; r < 4; ++r) {
          #pragma unroll
          for (int k = 0; k < 3; ++k) {
            const int bp = bo[k][0], bq = bo[k][1];
            const int cp = co[k][0], cq = co[k][1];
            const int bdi = (r == 0) ? bp : (r == 1) ? bq : (r == 2) ? -bp : -bq;
            const int bdj = (r == 0) ? bq : (r == 1) ? -bp : (r == 2) ? -bq : bp;
            const int cdi = (r == 0) ? cp : (r == 1) ? cq : (r == 2) ? -cp : -cq;
            const int cdj = (r == 0) ? cq : (r == 1) ? -cp : (r == 2) ? -cq : cp;
            const int bv = n[pi + 2 + bdi][pj + 2 + bdj];
            const int cv = n[pi + 2 + cdi][pj + 2 + cdj];
            const int idx = (k << 12) | (av << 8) | (bv << 4) | cv;
            half4 h = lut[idx];
            const float x = (float)h.x, y = (float)h.y;
            const float z = (float)h.z, w = (float)h.w;
            float* o = acc[pi][pj];
            if (r == 0)      { o[0] += x; o[1] += y; o[2] += z; o[3] += w; }
            else if (r == 1) { o[0] += z; o[1] += x; o[2] += w; o[3] += y; }
            else if (r == 2) { o[0] += w; o[1] += z; o[2] += y; o[3] += x; }
            else             { o[0] += y; o[1] += w; o[2] += x; o[3] += z; }
          }
        }
      }
    }

    // 4) store: 4 output rows x float4 (covers the 2x2 pixel patch upsampled)
    const float s = 1.0f / 3.0f;
    const int oy = by0 * 2 + ty * 4;
    const int ox = bx0 * 2 + tx * 4;
    float4* o4 = (float4*)out;
    o4[((oy + 0) * ONW + ox) >> 2] =
        make_float4(acc[0][0][0] * s, acc[0][0][1] * s, acc[0][1][0] * s, acc[0][1][1] * s);
    o4[((oy + 1) * ONW + ox) >> 2] =
        make_float4(acc[0][0][2] * s, acc[0][0][3] * s, acc[0][1][2] * s, acc[0][1][3] * s);
    o4[((oy + 2) * ONW + ox) >> 2] =
        make_float4(acc[1][0][0] * s, acc[1][0][1] * s, acc[1][1][0] * s, acc[1][1][1] * s);
    o4[((oy + 3) * ONW + ox) >> 2] =
        make_float4(acc[1][0][2] * s, acc[1][0][3] * s, acc[1][1][2] * s, acc[1][1][3] * s);
}

extern "C" void kernel_launch(void* const* d_in, const int* in_sizes, int n_in,
                              void* d_out, int out_size, void* d_ws, size_t ws_size,
                              hipStream_t stream)
{
    const int* img = (const int*)d_in[0];
    const float4* w4 = (const float4*)d_in[1];
    float* out = (float*)d_out;
    hipFuncSetAttribute(reinterpret_cast<const void*>(hdblut_kernel),
                        hipFuncAttributeMaxDynamicSharedMemorySize, SMEM_BYTES);
    hdblut_kernel<<<dim3(32, 32), dim3(32, 32), SMEM_BYTES, stream>>>(img, w4, out);
}

// Round 4
// 102.787 us; speedup vs baseline: 2.2629x; 1.1572x over previous
//
#include <hip/hip_runtime.h>
#include <hip/hip_fp16.h>

#define N 2048
#define ONW 4096
#define TW 128                        // tile width (pixels)
#define TH 32                        // tile height (pixels)
#define HW 132                        // halo tile width (ints)
#define HH 36                        // halo tile height
#define HELEMS (HW * HH)              // 4752
#define LUT_ENTRIES 12288
#define LUT_BYTES (LUT_ENTRIES * 8)   // 98304
#define SMEM_BYTES (LUT_BYTES + 2 * HELEMS * 4)  // 136320 <= 160K

typedef _Float16 half4v __attribute__((ext_vector_type(4)));
typedef float fvec4 __attribute__((ext_vector_type(4)));

__device__ __forceinline__ int reflect(int i) {
    i = i < 0 ? -i : i;
    return i >= N ? 2 * N - 2 - i : i;
}

__global__ __launch_bounds__(1024, 4) void hdblut_kernel(
    const int* __restrict__ img, const float4* __restrict__ w4,
    float* __restrict__ out)
{
    extern __shared__ unsigned char smem[];
    half4v* lut = (half4v*)smem;
    int* bufs = (int*)(smem + LUT_BYTES);

    const int tx = threadIdx.x;            // 0..63  (one wave = one ty row)
    const int ty = threadIdx.y;            // 0..15
    const int tid = ty * 64 + tx;
    const int x0 = (int)(blockIdx.x & 15) * TW;        // 16 x-strips
    const int y0 = (int)(blockIdx.x >> 4) * (TH * 4);  // 16 y-bands, 4 tiles each

    // 1) fp32 -> fp16 LUT into LDS (once per block)
    #pragma unroll
    for (int i = 0; i < 12; ++i) {
        int j = tid + i * 1024;
        float4 v = w4[j];
        half4v h;
        h.x = (_Float16)v.x; h.y = (_Float16)v.y;
        h.z = (_Float16)v.z; h.w = (_Float16)v.w;
        lut[j] = h;
    }

    // 2) tile 0 halo load (direct to LDS)
    for (int e = tid; e < HELEMS; e += 1024) {
        int rr = e / HW, cc = e - rr * HW;
        bufs[e] = img[reflect(y0 + rr - 2) * N + reflect(x0 + cc - 2)];
    }
    __syncthreads();

    const int bo[3][2] = {{0, 1}, {1, 1}, {1, 2}};
    const int co[3][2] = {{0, 2}, {2, 2}, {2, 1}};
    const float s = 1.0f / 3.0f;
    fvec4* o4 = (fvec4*)out;

    int pre[5];
    #pragma unroll 1
    for (int t = 0; t < 4; ++t) {
        int* cur = bufs + (t & 1) * HELEMS;
        int* nxt = bufs + ((t + 1) & 1) * HELEMS;

        // prefetch next tile into registers (latency hidden by compute)
        if (t < 3) {
            const int yb = y0 + (t + 1) * TH;
            #pragma unroll
            for (int u = 0; u < 5; ++u) {
                int e = tid + u * 1024;
                if (e < HELEMS) {
                    int rr = e / HW, cc = e - rr * HW;
                    pre[u] = img[reflect(yb + rr - 2) * N + reflect(x0 + cc - 2)];
                }
            }
        }

        // 3) 6x6 neighborhood for this thread's 2x2 pixel patch
        int n[6][6];
        {
            const int r0 = 2 * ty, c0 = 2 * tx;
            #pragma unroll
            for (int r = 0; r < 6; ++r)
                #pragma unroll
                for (int j = 0; j < 3; ++j) {
                    int2 t2 = *(const int2*)&cur[(r0 + r) * HW + c0 + 2 * j];
                    n[r][2 * j] = t2.x; n[r][2 * j + 1] = t2.y;
                }
        }

        float acc[2][2][4];
        #pragma unroll
        for (int i = 0; i < 2; ++i)
            #pragma unroll
            for (int j = 0; j < 2; ++j)
                #pragma unroll
                for (int c = 0; c < 4; ++c) acc[i][j][c] = 0.f;

        #pragma unroll
        for (int pi = 0; pi < 2; ++pi) {
          #pragma unroll
          for (int pj = 0; pj < 2; ++pj) {
            const int abase = n[2 + pi][2 + pj] << 8;
            #pragma unroll
            for (int r = 0; r < 4; ++r) {
              #pragma unroll
              for (int k = 0; k < 3; ++k) {
                const int bp = bo[k][0], bq = bo[k][1];
                const int cp = co[k][0], cq = co[k][1];
                const int bdi = (r == 0) ? bp : (r == 1) ? bq : (r == 2) ? -bp : -bq;
                const int bdj = (r == 0) ? bq : (r == 1) ? -bp : (r == 2) ? -bq : bp;
                const int cdi = (r == 0) ? cp : (r == 1) ? cq : (r == 2) ? -cp : -cq;
                const int cdj = (r == 0) ? cq : (r == 1) ? -cp : (r == 2) ? -cq : cp;
                const int bv = n[pi + 2 + bdi][pj + 2 + bdj];
                const int cv = n[pi + 2 + cdi][pj + 2 + cdj];
                half4v h = lut[(k << 12) | abase | (bv << 4) | cv];
                const float x = (float)h.x, y = (float)h.y;
                const float z = (float)h.z, w = (float)h.w;
                float* o = acc[pi][pj];
                if (r == 0)      { o[0] += x; o[1] += y; o[2] += z; o[3] += w; }
                else if (r == 1) { o[0] += z; o[1] += x; o[2] += w; o[3] += y; }
                else if (r == 2) { o[0] += w; o[1] += z; o[2] += y; o[3] += x; }
                else             { o[0] += y; o[1] += w; o[2] += x; o[3] += z; }
              }
            }
          }
        }

        // 4) wave-contiguous nontemporal stores (1 KiB per wave per row)
        const int py = y0 + t * TH + 2 * ty;
        const int ox = (x0 + 2 * tx) * 2;
        {
            fvec4 v0 = {acc[0][0][0] * s, acc[0][0][1] * s, acc[0][1][0] * s, acc[0][1][1] * s};
            fvec4 v1 = {acc[0][0][2] * s, acc[0][0][3] * s, acc[0][1][2] * s, acc[0][1][3] * s};
            fvec4 v2 = {acc[1][0][0] * s, acc[1][0][1] * s, acc[1][1][0] * s, acc[1][1][1] * s};
            fvec4 v3 = {acc[1][0][2] * s, acc[1][0][3] * s, acc[1][1][2] * s, acc[1][1][3] * s};
            __builtin_nontemporal_store(v0, &o4[((2 * py + 0) * ONW + ox) >> 2]);
            __builtin_nontemporal_store(v1, &o4[((2 * py + 1) * ONW + ox) >> 2]);
            __builtin_nontemporal_store(v2, &o4[((2 * py + 2) * ONW + ox) >> 2]);
            __builtin_nontemporal_store(v3, &o4[((2 * py + 3) * ONW + ox) >> 2]);
        }

        // commit prefetched tile to the other LDS buffer
        if (t < 3) {
            #pragma unroll
            for (int u = 0; u < 5; ++u) {
                int e = tid + u * 1024;
                if (e < HELEMS) nxt[e] = pre[u];
            }
        }
        __syncthreads();
    }
}

extern "C" void kernel_launch(void* const* d_in, const int* in_sizes, int n_in,
                              void* d_out, int out_size, void* d_ws, size_t ws_size,
                              hipStream_t stream)
{
    const int* img = (const int*)d_in[0];
    const float4* w4 = (const float4*)d_in[1];
    float* out = (float*)d_out;
    (void)hipFuncSetAttribute(reinterpret_cast<const void*>(hdblut_kernel),
                              hipFuncAttributeMaxDynamicSharedMemorySize, SMEM_BYTES);
    hdblut_kernel<<<dim3(256), dim3(64, 16), SMEM_BYTES, stream>>>(img, w4, out);
}

// Round 5
// 98.217 us; speedup vs baseline: 2.3682x; 1.0465x over previous
//
#include <hip/hip_runtime.h>
#include <hip/hip_fp16.h>

#define N 2048
#define ONW 4096
#define TW 128                        // tile width (pixels)
#define TH 32                         // tile height (pixels)
#define HW 132                        // halo tile width (ints)
#define HH 36                         // halo tile height
#define HELEMS (HW * HH)              // 4752
#define LUT_ENTRIES 12288
#define LUT_BYTES (LUT_ENTRIES * 8)   // 98304
#define SMEM_BYTES (LUT_BYTES + 2 * HELEMS * 4)  // 136320 <= 160K

typedef _Float16 half4v __attribute__((ext_vector_type(4)));
typedef float fvec4 __attribute__((ext_vector_type(4)));

__device__ __forceinline__ int reflect(int i) {
    i = i < 0 ? -i : i;
    return i >= N ? 2 * N - 2 - i : i;
}

__global__ __launch_bounds__(1024, 4) void hdblut_kernel(
    const int* __restrict__ img, const float4* __restrict__ w4,
    float* __restrict__ out)
{
    extern __shared__ unsigned char smem[];
    half4v* lut = (half4v*)smem;
    int* bufs = (int*)(smem + LUT_BYTES);

    const int tx = threadIdx.x;            // 0..63  (one wave = one ty row)
    const int ty = threadIdx.y;            // 0..15
    const int tid = ty * 64 + tx;
    const int x0 = (int)(blockIdx.x & 15) * TW;        // 16 x-strips
    const int y0 = (int)(blockIdx.x >> 4) * (TH * 4);  // 16 y-bands, 4 tiles each

    // 1) fp32 -> fp16 LUT into LDS (once per block)
    #pragma unroll
    for (int i = 0; i < 12; ++i) {
        int j = tid + i * 1024;
        float4 v = w4[j];
        half4v h;
        h.x = (_Float16)v.x; h.y = (_Float16)v.y;
        h.z = (_Float16)v.z; h.w = (_Float16)v.w;
        lut[j] = h;
    }

    // 2) tile 0 halo load (direct to LDS)
    for (int e = tid; e < HELEMS; e += 1024) {
        int rr = e / HW, cc = e - rr * HW;
        bufs[e] = img[reflect(y0 + rr - 2) * N + reflect(x0 + cc - 2)];
    }
    __syncthreads();

    const int bo[3][2] = {{0, 1}, {1, 1}, {1, 2}};
    const int co[3][2] = {{0, 2}, {2, 2}, {2, 1}};
    const float s = 1.0f / 3.0f;
    fvec4* o4 = (fvec4*)out;

    int pre[5];
    #pragma unroll 1
    for (int t = 0; t < 4; ++t) {
        int* cur = bufs + (t & 1) * HELEMS;
        int* nxt = bufs + ((t + 1) & 1) * HELEMS;

        // prefetch next tile into registers (latency hidden by compute)
        if (t < 3) {
            const int yb = y0 + (t + 1) * TH;
            #pragma unroll
            for (int u = 0; u < 5; ++u) {
                int e = tid + u * 1024;
                if (e < HELEMS) {
                    int rr = e / HW, cc = e - rr * HW;
                    pre[u] = img[reflect(yb + rr - 2) * N + reflect(x0 + cc - 2)];
                }
            }
        }

        // 3) 6x6 neighborhood for this thread's 2x2 pixel patch
        int n[6][6];
        {
            const int r0 = 2 * ty, c0 = 2 * tx;
            #pragma unroll
            for (int r = 0; r < 6; ++r)
                #pragma unroll
                for (int j = 0; j < 3; ++j) {
                    int2 t2 = *(const int2*)&cur[(r0 + r) * HW + c0 + 2 * j];
                    n[r][2 * j] = t2.x; n[r][2 * j + 1] = t2.y;
                }
        }

        float acc[2][2][4];
        #pragma unroll
        for (int i = 0; i < 2; ++i)
            #pragma unroll
            for (int j = 0; j < 2; ++j)
                #pragma unroll
                for (int c = 0; c < 4; ++c) acc[i][j][c] = 0.f;

        #pragma unroll
        for (int pi = 0; pi < 2; ++pi) {
          #pragma unroll
          for (int pj = 0; pj < 2; ++pj) {
            const int abase = n[2 + pi][2 + pj] << 8;

            // (a) compute all 12 LUT indices
            int idx[12];
            #pragma unroll
            for (int r = 0; r < 4; ++r) {
              #pragma unroll
              for (int k = 0; k < 3; ++k) {
                const int bp = bo[k][0], bq = bo[k][1];
                const int cp = co[k][0], cq = co[k][1];
                const int bdi = (r == 0) ? bp : (r == 1) ? bq : (r == 2) ? -bp : -bq;
                const int bdj = (r == 0) ? bq : (r == 1) ? -bp : (r == 2) ? -bq : bp;
                const int cdi = (r == 0) ? cp : (r == 1) ? cq : (r == 2) ? -cp : -cq;
                const int cdj = (r == 0) ? cq : (r == 1) ? -cp : (r == 2) ? -cq : cp;
                const int bv = n[pi + 2 + bdi][pj + 2 + bdj];
                const int cv = n[pi + 2 + cdi][pj + 2 + cdj];
                idx[r * 3 + k] = (k << 12) | abase | (bv << 4) | cv;
              }
            }

            // (b) issue all 12 gathers back-to-back (overlapped LDS latency)
            half4v v[12];
            #pragma unroll
            for (int i = 0; i < 12; ++i) v[i] = lut[idx[i]];

            // (c) fp16 pre-sum per rotation (shared permutation), then fp32 acc
            float* o = acc[pi][pj];
            #pragma unroll
            for (int r = 0; r < 4; ++r) {
                half4v S = v[3 * r] + v[3 * r + 1] + v[3 * r + 2];
                const float x = (float)S.x, y = (float)S.y;
                const float z = (float)S.z, w = (float)S.w;
                if (r == 0)      { o[0] += x; o[1] += y; o[2] += z; o[3] += w; }
                else if (r == 1) { o[0] += z; o[1] += x; o[2] += w; o[3] += y; }
                else if (r == 2) { o[0] += w; o[1] += z; o[2] += y; o[3] += x; }
                else             { o[0] += y; o[1] += w; o[2] += x; o[3] += z; }
            }
          }
        }

        // 4) wave-contiguous stores (1 KiB per wave per row)
        const int py = y0 + t * TH + 2 * ty;
        const int ox = (x0 + 2 * tx) * 2;
        {
            fvec4 v0 = {acc[0][0][0] * s, acc[0][0][1] * s, acc[0][1][0] * s, acc[0][1][1] * s};
            fvec4 v1 = {acc[0][0][2] * s, acc[0][0][3] * s, acc[0][1][2] * s, acc[0][1][3] * s};
            fvec4 v2 = {acc[1][0][0] * s, acc[1][0][1] * s, acc[1][1][0] * s, acc[1][1][1] * s};
            fvec4 v3 = {acc[1][0][2] * s, acc[1][0][3] * s, acc[1][1][2] * s, acc[1][1][3] * s};
            o4[((2 * py + 0) * ONW + ox) >> 2] = v0;
            o4[((2 * py + 1) * ONW + ox) >> 2] = v1;
            o4[((2 * py + 2) * ONW + ox) >> 2] = v2;
            o4[((2 * py + 3) * ONW + ox) >> 2] = v3;
        }

        // commit prefetched tile to the other LDS buffer
        if (t < 3) {
            #pragma unroll
            for (int u = 0; u < 5; ++u) {
                int e = tid + u * 1024;
                if (e < HELEMS) nxt[e] = pre[u];
            }
        }
        __syncthreads();
    }
}

extern "C" void kernel_launch(void* const* d_in, const int* in_sizes, int n_in,
                              void* d_out, int out_size, void* d_ws, size_t ws_size,
                              hipStream_t stream)
{
    const int* img = (const int*)d_in[0];
    const float4* w4 = (const float4*)d_in[1];
    float* out = (float*)d_out;
    (void)hipFuncSetAttribute(reinterpret_cast<const void*>(hdblut_kernel),
                              hipFuncAttributeMaxDynamicSharedMemorySize, SMEM_BYTES);
    hdblut_kernel<<<dim3(256), dim3(64, 16), SMEM_BYTES, stream>>>(img, w4, out);
}